// Round 6
// baseline (229.142 us; speedup 1.0000x reference)
//
#include <hip/hip_runtime.h>
#include <hip/hip_bf16.h>
#include <stdint.h>

#define B_ 4
#define T_ 2048
#define C_ 1024
#define H_ 16
#define D_ 64

typedef short bf16x8 __attribute__((ext_vector_type(8)));
typedef short bf16x4 __attribute__((ext_vector_type(4)));
typedef float f32x4 __attribute__((ext_vector_type(4)));
typedef unsigned short u16;

#define HAS_M16 __has_builtin(__builtin_amdgcn_mfma_f32_16x16x16bf16_1k)

// log2(e)/sqrt(D): folded into Q at the qkv epilogue -> scores in exp2 domain.
#define QSCALE 0.18033688011112042f

__device__ __forceinline__ u16 f2bf(float f) {
    __hip_bfloat16 h = __float2bfloat16(f);
    return *reinterpret_cast<u16*>(&h);
}

__device__ __forceinline__ float fexp2(float x) {
    float r;
    asm("v_exp_f32 %0, %1" : "=v"(r) : "v"(x));
    return r;
}

__device__ __forceinline__ void gload16(const void* g, void* l) {
    __builtin_amdgcn_global_load_lds(
        (const __attribute__((address_space(1))) unsigned int*)g,
        (__attribute__((address_space(3))) unsigned int*)l, 16, 0, 0);
}

// ---------------- cast fp32 -> bf16 (same layout) ----------------
__global__ void k_cast_bf16(const float* __restrict__ src, u16* __restrict__ dst, int n) {
    int i = (blockIdx.x * blockDim.x + threadIdx.x) * 4;
    if (i >= n) return;
    float4 f = *reinterpret_cast<const float4*>(src + i);
    ushort4 o;
    o.x = f2bf(f.x); o.y = f2bf(f.y); o.z = f2bf(f.z); o.w = f2bf(f.w);
    *reinterpret_cast<ushort4*>(dst + i) = o;
}

// ---------------- transpose + cast: [R][Cc] f32 -> [Cc][R] bf16 ----------------
__global__ void k_transpose_bf16(const float* __restrict__ src, u16* __restrict__ dst,
                                 int R, int Cc) {
    __shared__ float tile[32][33];
    int c0 = blockIdx.x * 32, r0 = blockIdx.y * 32;
    int tx = threadIdx.x, ty = threadIdx.y;
#pragma unroll
    for (int i = 0; i < 4; i++)
        tile[ty + i * 8][tx] = src[(size_t)(r0 + ty + i * 8) * Cc + c0 + tx];
    __syncthreads();
#pragma unroll
    for (int i = 0; i < 4; i++)
        dst[(size_t)(c0 + ty + i * 8) * R + r0 + tx] = f2bf(tile[tx][ty + i * 8]);
}

// ---------------- GEMM (m97-style, reverted round-4 known-good) ----------------
// C[M,N] = A[M,K] * Bt[N,K]^T + bias. 128x128 tile, BK=64, 4 waves of 64x64.
// EPI 0: fp32 out (out-projection).  EPI 1: route to q/k/v ws (qkv projection).
template <int EPI>
__launch_bounds__(256, 2)
__global__ void k_gemm(const u16* __restrict__ A, const u16* __restrict__ Bt,
                       const float* __restrict__ bias, int K, int N,
                       float* __restrict__ outf,
                       u16* __restrict__ qw, u16* __restrict__ kw, u16* __restrict__ vw) {
    __shared__ u16 As[128 * 64];
    __shared__ u16 Bs[128 * 64];
    const int tid = threadIdx.x;
    const int lane = tid & 63, w = tid >> 6;
    const int m0 = blockIdx.x * 128, n0 = blockIdx.y * 128;
    const int wm = (w >> 1) * 64, wn = (w & 1) * 64;
    const int lr = lane & 15, lg = lane >> 4;

    f32x4 acc[4][4];
#pragma unroll
    for (int i = 0; i < 4; i++)
#pragma unroll
        for (int j = 0; j < 4; j++) acc[i][j] = (f32x4){0.f, 0.f, 0.f, 0.f};

    const int nk = K >> 6;
    for (int kt = 0; kt < nk; ++kt) {
        const int k0 = kt * 64;
#pragma unroll
        for (int i = 0; i < 4; i++) {
            int c = i * 256 + tid;
            int row = c >> 3, k8 = (c & 7) << 3;
            gload16(A + (size_t)(m0 + row) * K + k0 + k8, (char*)As + i * 4096 + w * 1024);
            gload16(Bt + (size_t)(n0 + row) * K + k0 + k8, (char*)Bs + i * 4096 + w * 1024);
        }
        __syncthreads();
#pragma unroll
        for (int kk = 0; kk < 2; ++kk) {
            bf16x8 af[4], bfr[4];
#pragma unroll
            for (int mf = 0; mf < 4; ++mf)
                af[mf] = *reinterpret_cast<const bf16x8*>(&As[(wm + mf * 16 + lr) * 64 + kk * 32 + lg * 8]);
#pragma unroll
            for (int nf = 0; nf < 4; ++nf)
                bfr[nf] = *reinterpret_cast<const bf16x8*>(&Bs[(wn + nf * 16 + lr) * 64 + kk * 32 + lg * 8]);
#pragma unroll
            for (int mf = 0; mf < 4; ++mf)
#pragma unroll
                for (int nf = 0; nf < 4; ++nf)
                    acc[mf][nf] = __builtin_amdgcn_mfma_f32_16x16x32_bf16(af[mf], bfr[nf], acc[mf][nf], 0, 0, 0);
        }
        __syncthreads();
    }

    if (EPI == 0) {
#pragma unroll
        for (int mf = 0; mf < 4; ++mf)
#pragma unroll
            for (int nf = 0; nf < 4; ++nf) {
                int ng = n0 + wn + nf * 16 + lr;
                float bs = bias[ng];
#pragma unroll
                for (int r = 0; r < 4; ++r) {
                    int mg = m0 + wm + mf * 16 + lg * 4 + r;
                    outf[(size_t)mg * N + ng] = acc[mf][nf][r] + bs;
                }
            }
    } else {
        const int sec = n0 >> 10;  // 0:q 1:k 2:v — uniform per block
        const float sc = (sec == 0) ? QSCALE : 1.0f;  // Q prescaled into exp2 domain
#pragma unroll
        for (int mf = 0; mf < 4; ++mf)
#pragma unroll
            for (int nf = 0; nf < 4; ++nf) {
                int ng = n0 + wn + nf * 16 + lr;
                float bs = bias[ng];
                int hd = ng & 1023;
                int h = hd >> 6, d = hd & 63;
                int mgb = m0 + wm + mf * 16 + lg * 4;
                int b = mgb >> 11, t0v = mgb & 2047;
                if (sec == 2) {
                    ushort4 pk;
                    pk.x = f2bf(acc[mf][nf][0] + bs);
                    pk.y = f2bf(acc[mf][nf][1] + bs);
                    pk.z = f2bf(acc[mf][nf][2] + bs);
                    pk.w = f2bf(acc[mf][nf][3] + bs);
                    *reinterpret_cast<ushort4*>(&vw[((size_t)(b * H_ + h) * D_ + d) * T_ + t0v]) = pk;
                } else {
                    u16* dst = (sec == 0) ? qw : kw;
#pragma unroll
                    for (int r = 0; r < 4; ++r)
                        dst[((size_t)(b * H_ + h) * T_ + t0v + r) * D_ + d] = f2bf((acc[mf][nf][r] + bs) * sc);
                }
            }
    }
}

// ---------------- flash attention: 8 waves x 16 q-rows ----------------
// Same K/V LDS staging (2-dbuf, XOR chunk-swizzle, gload_lds w=16, counted
// vmcnt(2)) but 512-thread blocks: 8 waves each owning 16 q-rows. Halved
// per-wave state (<=64 VGPR) + grid 1024 = 4 blocks/CU x 8 waves -> up to
// 32 waves/CU (was 16): doubles TLP for the serial QK->exp->pack->PV chain.
// Softmax: no-max exp2 (scores bounded ~|12|, shift-invariance => exact).
#if HAS_M16
__launch_bounds__(512, 8)
#else
__launch_bounds__(512, 4)
#endif
__global__ void k_attn(const u16* __restrict__ qw, const u16* __restrict__ kw,
                       const u16* __restrict__ vw, u16* __restrict__ attn) {
    __shared__ u16 Ks[2][64][64];   // [buf][key][d]   rows 128B, chunk-swizzled
    __shared__ u16 Vs[2][64][64];   // [buf][d][key]
#if !HAS_M16
    __shared__ u16 pshm[8][16][64];
#endif
    const int tid = threadIdx.x, lane = tid & 63, w = tid >> 6;
    const int lr = lane & 15, lg = lane >> 4;
    const int bid = blockIdx.x;
    const int logical = (bid & 7) * 128 + (bid >> 3);  // bijective: 1024 = 8*128
    const int bh = logical >> 4, qb = logical & 15;
    const int b = bh >> 4, h = bh & 15;
    const int q0 = qb * 128 + w * 16;
    const u16* qbase = qw + (size_t)bh * T_ * D_;
    const u16* kbase = kw + (size_t)bh * T_ * D_;
    const u16* vbase = vw + (size_t)bh * D_ * T_;

    // Q as B-operand: col = q-row (lr), k = d contiguous
    bf16x8 qf[2];
#pragma unroll
    for (int kd = 0; kd < 2; kd++)
        qf[kd] = *reinterpret_cast<const bf16x8*>(
            &qbase[(size_t)(q0 + lr) * D_ + kd * 32 + lg * 8]);

    // stage one 64x64 tile (8KB): 512 threads x 1 chunk; wave w covers rows
    // w*8..w*8+7 -> LDS bytes w*1024 + lane*16 (linear dest, source swizzled)
    const int srow = tid >> 3, sch = tid & 7;
    const int sgch = sch ^ (srow & 7);
    auto stageK = [&](int kt, int buf) {
        gload16(kbase + ((size_t)(kt * 64 + srow) * 64 + sgch * 8),
                (char*)&Ks[buf][0][0] + w * 1024);
    };
    auto stageV = [&](int kt, int buf) {
        gload16(vbase + ((size_t)srow * T_ + kt * 64 + sgch * 8),
                (char*)&Vs[buf][0][0] + w * 1024);
    };

    f32x4 o[4];
#pragma unroll
    for (int md = 0; md < 4; md++) o[md] = (f32x4){0.f, 0.f, 0.f, 0.f};
    float l_run = 0.f;  // per-lane partial sum (keys this lane holds)

    const int NT = T_ / 64;
    stageK(0, 0);
    stageV(0, 0);

    for (int kt = 0; kt < NT; ++kt) {
        const int cur = kt & 1;
        if (kt + 1 < NT) {
            stageK(kt + 1, cur ^ 1);
            stageV(kt + 1, cur ^ 1);
            asm volatile("s_waitcnt vmcnt(2)" ::: "memory");  // cur done, next in flight
        } else {
            asm volatile("s_waitcnt vmcnt(0)" ::: "memory");
        }
        __builtin_amdgcn_s_barrier();

        // QK^T: S^T = K * Q^T; ka loaded just-in-time (short live ranges)
        f32x4 s[4];
#pragma unroll
        for (int mk = 0; mk < 4; mk++) s[mk] = (f32x4){0.f, 0.f, 0.f, 0.f};
        __builtin_amdgcn_s_setprio(1);
#pragma unroll
        for (int mk = 0; mk < 4; mk++) {
            int row = mk * 16 + lr;
#pragma unroll
            for (int kd = 0; kd < 2; kd++) {
                int colb = (kd * 64 + lg * 16) ^ ((row & 7) << 4);
                bf16x8 ka = *reinterpret_cast<const bf16x8*>(
                    (const char*)&Ks[cur][0][0] + row * 128 + colb);
                s[mk] = __builtin_amdgcn_mfma_f32_16x16x32_bf16(ka, qf[kd], s[mk], 0, 0, 0);
            }
        }
        __builtin_amdgcn_s_setprio(0);

        // softmax numerator: p = exp2(s) raw — no max, no subtraction.
#if HAS_M16
        bf16x4 pfrag[4];
#endif
        {
            float psum = 0.f;
#pragma unroll
            for (int mk = 0; mk < 4; mk++) {
                float p0 = fexp2(s[mk][0]);
                float p1 = fexp2(s[mk][1]);
                float p2 = fexp2(s[mk][2]);
                float p3 = fexp2(s[mk][3]);
                psum += (p0 + p1) + (p2 + p3);
#if HAS_M16
                pfrag[mk] = (bf16x4){(short)f2bf(p0), (short)f2bf(p1),
                                     (short)f2bf(p2), (short)f2bf(p3)};
#else
                ushort4 pk;
                pk.x = f2bf(p0); pk.y = f2bf(p1); pk.z = f2bf(p2); pk.w = f2bf(p3);
                int pcolb = (mk * 32 + lg * 8) ^ ((lr & 7) << 4);
                *reinterpret_cast<ushort4*>((char*)&pshm[w][0][0] + lr * 128 + pcolb) = pk;
#endif
            }
            l_run += psum;
        }

#if HAS_M16
        // PV with K=16 MFMA: P fragment layout (keys lg*4+r) == A/B k-layout.
        __builtin_amdgcn_s_setprio(1);
#pragma unroll
        for (int md = 0; md < 4; md++) {
            int row = md * 16 + lr;
#pragma unroll
            for (int mk = 0; mk < 4; mk++) {
                int colb = (mk * 32 + lg * 8) ^ ((row & 7) << 4);
                bf16x4 va = *reinterpret_cast<const bf16x4*>(
                    (const char*)&Vs[cur][0][0] + row * 128 + colb);
                o[md] = __builtin_amdgcn_mfma_f32_16x16x16bf16_1k(va, pfrag[mk], o[md], 0, 0, 0);
            }
        }
        __builtin_amdgcn_s_setprio(0);
#else
        asm volatile("s_waitcnt lgkmcnt(0)" ::: "memory");
        bf16x8 pb[2];
#pragma unroll
        for (int kk = 0; kk < 2; kk++) {
            int pcolb = (kk * 64 + lg * 16) ^ ((lr & 7) << 4);
            pb[kk] = *reinterpret_cast<const bf16x8*>(
                (const char*)&pshm[w][0][0] + lr * 128 + pcolb);
        }
        __builtin_amdgcn_s_setprio(1);
#pragma unroll
        for (int md = 0; md < 4; md++) {
            int row = md * 16 + lr;
#pragma unroll
            for (int kk = 0; kk < 2; kk++) {
                int colb = (kk * 64 + lg * 16) ^ ((row & 7) << 4);
                bf16x8 va = *reinterpret_cast<const bf16x8*>(
                    (const char*)&Vs[cur][0][0] + row * 128 + colb);
                o[md] = __builtin_amdgcn_mfma_f32_16x16x32_bf16(va, pb[kk], o[md], 0, 0, 0);
            }
        }
        __builtin_amdgcn_s_setprio(0);
#endif

        __builtin_amdgcn_s_barrier();  // all waves done reading buf before overwrite
    }

    // epilogue: reduce l across the 4 lanes holding this q-row, then normalize.
    {
        float l = l_run;
        l += __shfl_xor(l, 16);
        l += __shfl_xor(l, 32);
        float rinv = 1.f / l;
        int q = q0 + lr;
#pragma unroll
        for (int md = 0; md < 4; md++) {
            int d0 = md * 16 + lg * 4;
            ushort4 pk;
            pk.x = f2bf(o[md][0] * rinv);
            pk.y = f2bf(o[md][1] * rinv);
            pk.z = f2bf(o[md][2] * rinv);
            pk.w = f2bf(o[md][3] * rinv);
            *reinterpret_cast<ushort4*>(&attn[((size_t)(b * T_ + q)) * C_ + h * D_ + d0]) = pk;
        }
    }
}

extern "C" void kernel_launch(void* const* d_in, const int* in_sizes, int n_in,
                              void* d_out, int out_size, void* d_ws, size_t ws_size,
                              hipStream_t stream) {
    const float* y = (const float*)d_in[0];
    const float* W_attn = (const float*)d_in[1];
    const float* b_attn = (const float*)d_in[2];
    const float* W_proj = (const float*)d_in[3];
    const float* b_proj = (const float*)d_in[4];

    char* ws = (char*)d_ws;
    u16* y_bf = (u16*)(ws);                                // 16 MB
    u16* WaT  = (u16*)(ws + 16777216);                     // 6 MB  [3072][1024]
    u16* WpT  = (u16*)(ws + 16777216 + 6291456);           // 2 MB  [1024][1024]
    u16* q_ws = (u16*)(ws + 25165824);                     // 16 MB [B,H,T,D] (prescaled)
    u16* k_ws = (u16*)(ws + 25165824 + 16777216);          // 16 MB [B,H,T,D]
    u16* v_ws = (u16*)(ws + 25165824 + 33554432);          // 16 MB [B,H,D,T]
    u16* attn = (u16*)(ws + 25165824 + 50331648);          // 16 MB [B,T,C]

    k_cast_bf16<<<8192, 256, 0, stream>>>(y, y_bf, B_ * T_ * C_);
    k_transpose_bf16<<<dim3(96, 32), dim3(32, 8), 0, stream>>>(W_attn, WaT, 1024, 3072);
    k_transpose_bf16<<<dim3(32, 32), dim3(32, 8), 0, stream>>>(W_proj, WpT, 1024, 1024);
    k_gemm<1><<<dim3(64, 24), 256, 0, stream>>>(y_bf, WaT, b_attn, 1024, 3072,
                                                nullptr, q_ws, k_ws, v_ws);
    k_attn<<<1024, 512, 0, stream>>>(q_ws, k_ws, v_ws, attn);
    k_gemm<0><<<dim3(64, 8), 256, 0, stream>>>(attn, WpT, b_proj, 1024, 1024,
                                               (float*)d_out, nullptr, nullptr, nullptr);
}

// Round 7
// 200.109 us; speedup vs baseline: 1.1451x; 1.1451x over previous
//
#include <hip/hip_runtime.h>
#include <hip/hip_bf16.h>
#include <stdint.h>

#define B_ 4
#define T_ 2048
#define C_ 1024
#define H_ 16
#define D_ 64

typedef short bf16x8 __attribute__((ext_vector_type(8)));
typedef float f32x4 __attribute__((ext_vector_type(4)));
typedef unsigned short u16;

// log2(e)/sqrt(D): folded into Q at the qkv epilogue -> scores in exp2 domain.
#define QSCALE 0.18033688011112042f

__device__ __forceinline__ u16 f2bf(float f) {
    __hip_bfloat16 h = __float2bfloat16(f);
    return *reinterpret_cast<u16*>(&h);
}

__device__ __forceinline__ float fexp2(float x) {
    float r;
    asm("v_exp_f32 %0, %1" : "=v"(r) : "v"(x));
    return r;
}

__device__ __forceinline__ void gload16(const void* g, void* l) {
    __builtin_amdgcn_global_load_lds(
        (const __attribute__((address_space(1))) unsigned int*)g,
        (__attribute__((address_space(3))) unsigned int*)l, 16, 0, 0);
}

// ---------------- cast fp32 -> bf16 (same layout) ----------------
__global__ void k_cast_bf16(const float* __restrict__ src, u16* __restrict__ dst, int n) {
    int i = (blockIdx.x * blockDim.x + threadIdx.x) * 4;
    if (i >= n) return;
    float4 f = *reinterpret_cast<const float4*>(src + i);
    ushort4 o;
    o.x = f2bf(f.x); o.y = f2bf(f.y); o.z = f2bf(f.z); o.w = f2bf(f.w);
    *reinterpret_cast<ushort4*>(dst + i) = o;
}

// ---------------- transpose + cast: [R][Cc] f32 -> [Cc][R] bf16 ----------------
__global__ void k_transpose_bf16(const float* __restrict__ src, u16* __restrict__ dst,
                                 int R, int Cc) {
    __shared__ float tile[32][33];
    int c0 = blockIdx.x * 32, r0 = blockIdx.y * 32;
    int tx = threadIdx.x, ty = threadIdx.y;
#pragma unroll
    for (int i = 0; i < 4; i++)
        tile[ty + i * 8][tx] = src[(size_t)(r0 + ty + i * 8) * Cc + c0 + tx];
    __syncthreads();
#pragma unroll
    for (int i = 0; i < 4; i++)
        dst[(size_t)(c0 + ty + i * 8) * R + r0 + tx] = f2bf(tile[tx][ty + i * 8]);
}

// ---------------- GEMM (m97-style, known-good) ----------------
// C[M,N] = A[M,K] * Bt[N,K]^T + bias. 128x128 tile, BK=64, 4 waves of 64x64.
template <int EPI>
__launch_bounds__(256, 2)
__global__ void k_gemm(const u16* __restrict__ A, const u16* __restrict__ Bt,
                       const float* __restrict__ bias, int K, int N,
                       float* __restrict__ outf,
                       u16* __restrict__ qw, u16* __restrict__ kw, u16* __restrict__ vw) {
    __shared__ u16 As[128 * 64];
    __shared__ u16 Bs[128 * 64];
    const int tid = threadIdx.x;
    const int lane = tid & 63, w = tid >> 6;
    const int m0 = blockIdx.x * 128, n0 = blockIdx.y * 128;
    const int wm = (w >> 1) * 64, wn = (w & 1) * 64;
    const int lr = lane & 15, lg = lane >> 4;

    f32x4 acc[4][4];
#pragma unroll
    for (int i = 0; i < 4; i++)
#pragma unroll
        for (int j = 0; j < 4; j++) acc[i][j] = (f32x4){0.f, 0.f, 0.f, 0.f};

    const int nk = K >> 6;
    for (int kt = 0; kt < nk; ++kt) {
        const int k0 = kt * 64;
#pragma unroll
        for (int i = 0; i < 4; i++) {
            int c = i * 256 + tid;
            int row = c >> 3, k8 = (c & 7) << 3;
            gload16(A + (size_t)(m0 + row) * K + k0 + k8, (char*)As + i * 4096 + w * 1024);
            gload16(Bt + (size_t)(n0 + row) * K + k0 + k8, (char*)Bs + i * 4096 + w * 1024);
        }
        __syncthreads();
#pragma unroll
        for (int kk = 0; kk < 2; ++kk) {
            bf16x8 af[4], bfr[4];
#pragma unroll
            for (int mf = 0; mf < 4; ++mf)
                af[mf] = *reinterpret_cast<const bf16x8*>(&As[(wm + mf * 16 + lr) * 64 + kk * 32 + lg * 8]);
#pragma unroll
            for (int nf = 0; nf < 4; ++nf)
                bfr[nf] = *reinterpret_cast<const bf16x8*>(&Bs[(wn + nf * 16 + lr) * 64 + kk * 32 + lg * 8]);
#pragma unroll
            for (int mf = 0; mf < 4; ++mf)
#pragma unroll
                for (int nf = 0; nf < 4; ++nf)
                    acc[mf][nf] = __builtin_amdgcn_mfma_f32_16x16x32_bf16(af[mf], bfr[nf], acc[mf][nf], 0, 0, 0);
        }
        __syncthreads();
    }

    if (EPI == 0) {
#pragma unroll
        for (int mf = 0; mf < 4; ++mf)
#pragma unroll
            for (int nf = 0; nf < 4; ++nf) {
                int ng = n0 + wn + nf * 16 + lr;
                float bs = bias[ng];
#pragma unroll
                for (int r = 0; r < 4; ++r) {
                    int mg = m0 + wm + mf * 16 + lg * 4 + r;
                    outf[(size_t)mg * N + ng] = acc[mf][nf][r] + bs;
                }
            }
    } else {
        const int sec = n0 >> 10;  // 0:q 1:k 2:v — uniform per block
        const float sc = (sec == 0) ? QSCALE : 1.0f;  // Q prescaled into exp2 domain
#pragma unroll
        for (int mf = 0; mf < 4; ++mf)
#pragma unroll
            for (int nf = 0; nf < 4; ++nf) {
                int ng = n0 + wn + nf * 16 + lr;
                float bs = bias[ng];
                int hd = ng & 1023;
                int h = hd >> 6, d = hd & 63;
                int mgb = m0 + wm + mf * 16 + lg * 4;
                int b = mgb >> 11, t0v = mgb & 2047;
                if (sec == 2) {
                    ushort4 pk;
                    pk.x = f2bf(acc[mf][nf][0] + bs);
                    pk.y = f2bf(acc[mf][nf][1] + bs);
                    pk.z = f2bf(acc[mf][nf][2] + bs);
                    pk.w = f2bf(acc[mf][nf][3] + bs);
                    *reinterpret_cast<ushort4*>(&vw[((size_t)(b * H_ + h) * D_ + d) * T_ + t0v]) = pk;
                } else {
                    u16* dst = (sec == 0) ? qw : kw;
#pragma unroll
                    for (int r = 0; r < 4; ++r)
                        dst[((size_t)(b * H_ + h) * T_ + t0v + r) * D_ + d] = f2bf((acc[mf][nf][r] + bs) * sc);
                }
            }
    }
}

// ---------------- flash attention: 4 waves x 32 q-rows, all-x32 MFMA ----------------
// K/V LDS 2-dbuf staging (gload_lds w=16, counted vmcnt(4)).
// Permuted-K-row QK trick: A-rows fed as key = g*32 + (lr>>2)*8 + (lr&3) + t*4,
// so the QK C-fragment (keys lg*4+r per tile) lands as keys lg*8+e across the
// tileA/tileB pair == exactly the 16x16x32 B-operand k-layout. P then feeds PV
// via full-rate x32 MFMA with zero cross-lane movement (no LDS round-trip, no
// half-rate K=16 MFMA). K swizzle s(row)=(row&3)|((row>>3)&1)<<2 keeps the
// permuted read conflict-free (8 lanes/slot x 8 slots); V keeps (row&7).
// Softmax: no-max exp2 (scores bounded |s|<~12, shift-invariance => exact).
__launch_bounds__(256, 4)
__global__ void k_attn(const u16* __restrict__ qw, const u16* __restrict__ kw,
                       const u16* __restrict__ vw, u16* __restrict__ attn) {
    __shared__ u16 Ks[2][64][64];   // [buf][key][d]   rows 128B, sK-swizzled
    __shared__ u16 Vs[2][64][64];   // [buf][d][key]   rows 128B, (row&7)-swizzled
    const int tid = threadIdx.x, lane = tid & 63, w = tid >> 6;
    const int lr = lane & 15, lg = lane >> 4;
    const int bid = blockIdx.x;
    const int logical = (bid & 7) * 128 + (bid >> 3);  // bijective: 1024 = 8*128
    const int bh = logical >> 4, qb = logical & 15;
    const int b = bh >> 4, h = bh & 15;
    const int q0 = qb * 128 + w * 32;
    const u16* qbase = qw + (size_t)bh * T_ * D_;
    const u16* kbase = kw + (size_t)bh * T_ * D_;
    const u16* vbase = vw + (size_t)bh * D_ * T_;

    // Q as B-operand fragments: col = q-row (lr), k = d contiguous
    bf16x8 qf[2][2];
#pragma unroll
    for (int jq = 0; jq < 2; jq++)
#pragma unroll
        for (int kd = 0; kd < 2; kd++)
            qf[jq][kd] = *reinterpret_cast<const bf16x8*>(
                &qbase[(size_t)(q0 + jq * 16 + lr) * D_ + kd * 32 + lg * 8]);

    // K swizzle: s(row) = (row&3) | ((row>>3)&1)<<2  (XOR involution both sides)
    auto stageK = [&](int kt, int buf) {
#pragma unroll
        for (int i = 0; i < 2; i++) {
            int idx = i * 256 + tid;
            int row = idx >> 3, ch = idx & 7;
            int gch = ch ^ ((row & 3) | (((row >> 3) & 1) << 2));
            gload16(kbase + ((size_t)(kt * 64 + row) * 64 + gch * 8),
                    (char*)&Ks[buf][0][0] + i * 4096 + w * 1024);
        }
    };
    auto stageV = [&](int kt, int buf) {
#pragma unroll
        for (int i = 0; i < 2; i++) {
            int idx = i * 256 + tid;
            int row = idx >> 3, ch = idx & 7;
            int gch = ch ^ (row & 7);
            gload16(vbase + ((size_t)row * T_ + kt * 64 + gch * 8),
                    (char*)&Vs[buf][0][0] + i * 4096 + w * 1024);
        }
    };

    f32x4 o[4][2];
#pragma unroll
    for (int md = 0; md < 4; md++)
#pragma unroll
        for (int jq = 0; jq < 2; jq++) o[md][jq] = (f32x4){0.f, 0.f, 0.f, 0.f};
    float l_run[2] = {0.f, 0.f};  // per-lane partial sums

    // permuted A-row base for QK (per-lane constants)
    const int karow_base = ((lr >> 2) << 3) + (lr & 3);
    const int skl = ((lr & 3) | (((lr >> 2) & 1) << 2)) << 4;  // byte-XOR for ka reads

    const int NT = T_ / 64;
    stageK(0, 0);
    stageV(0, 0);

    for (int kt = 0; kt < NT; ++kt) {
        const int cur = kt & 1;
        if (kt + 1 < NT) {
            stageK(kt + 1, cur ^ 1);
            stageV(kt + 1, cur ^ 1);
            asm volatile("s_waitcnt vmcnt(4)" ::: "memory");  // cur done, next in flight
        } else {
            asm volatile("s_waitcnt vmcnt(0)" ::: "memory");
        }
        __builtin_amdgcn_s_barrier();

        bf16x8 pfrag[2][2];  // [jq][g] — x32 B-operand frags, keys g*32 + lg*8 + e
#pragma unroll
        for (int g = 0; g < 2; g++) {
            f32x4 st[2][2];  // [tile][jq]
#pragma unroll
            for (int t = 0; t < 2; t++)
#pragma unroll
                for (int jq = 0; jq < 2; jq++) st[t][jq] = (f32x4){0.f, 0.f, 0.f, 0.f};
            __builtin_amdgcn_s_setprio(1);
#pragma unroll
            for (int t = 0; t < 2; t++) {
                int row = g * 32 + karow_base + t * 4;
#pragma unroll
                for (int kd = 0; kd < 2; kd++) {
                    bf16x8 ka = *reinterpret_cast<const bf16x8*>(
                        (const char*)&Ks[cur][0][0] + row * 128 + ((kd * 64 + lg * 16) ^ skl));
#pragma unroll
                    for (int jq = 0; jq < 2; jq++)
                        st[t][jq] = __builtin_amdgcn_mfma_f32_16x16x32_bf16(ka, qf[jq][kd], st[t][jq], 0, 0, 0);
                }
            }
            __builtin_amdgcn_s_setprio(0);
            // p = exp2(s) raw (no max); pack straight into the x32 fragment
#pragma unroll
            for (int jq = 0; jq < 2; jq++) {
                float p0 = fexp2(st[0][jq][0]), p1 = fexp2(st[0][jq][1]);
                float p2 = fexp2(st[0][jq][2]), p3 = fexp2(st[0][jq][3]);
                float p4 = fexp2(st[1][jq][0]), p5 = fexp2(st[1][jq][1]);
                float p6 = fexp2(st[1][jq][2]), p7 = fexp2(st[1][jq][3]);
                l_run[jq] += ((p0 + p1) + (p2 + p3)) + ((p4 + p5) + (p6 + p7));
                pfrag[jq][g] = (bf16x8){(short)f2bf(p0), (short)f2bf(p1),
                                        (short)f2bf(p2), (short)f2bf(p3),
                                        (short)f2bf(p4), (short)f2bf(p5),
                                        (short)f2bf(p6), (short)f2bf(p7)};
            }
        }

        // PV at full x32 rate: o += V^T[g] * P^T[g]
#pragma unroll
        for (int g = 0; g < 2; g++) {
            bf16x8 va[4];
#pragma unroll
            for (int md = 0; md < 4; md++) {
                int row = md * 16 + lr;
                va[md] = *reinterpret_cast<const bf16x8*>(
                    (const char*)&Vs[cur][0][0] + row * 128 + ((g * 64 + lg * 16) ^ ((row & 7) << 4)));
            }
            __builtin_amdgcn_s_setprio(1);
#pragma unroll
            for (int md = 0; md < 4; md++)
#pragma unroll
                for (int jq = 0; jq < 2; jq++)
                    o[md][jq] = __builtin_amdgcn_mfma_f32_16x16x32_bf16(va[md], pfrag[jq][g], o[md][jq], 0, 0, 0);
            __builtin_amdgcn_s_setprio(0);
        }

        __builtin_amdgcn_s_barrier();  // all waves done reading buf before overwrite
    }

    // epilogue: reduce l across the 4 lanes holding this q-row, then normalize.
#pragma unroll
    for (int jq = 0; jq < 2; jq++) {
        float l = l_run[jq];
        l += __shfl_xor(l, 16);
        l += __shfl_xor(l, 32);
        float rinv = 1.f / l;
        int q = q0 + jq * 16 + lr;
#pragma unroll
        for (int md = 0; md < 4; md++) {
            int d0 = md * 16 + lg * 4;
            ushort4 pk;
            pk.x = f2bf(o[md][jq][0] * rinv);
            pk.y = f2bf(o[md][jq][1] * rinv);
            pk.z = f2bf(o[md][jq][2] * rinv);
            pk.w = f2bf(o[md][jq][3] * rinv);
            *reinterpret_cast<ushort4*>(&attn[((size_t)(b * T_ + q)) * C_ + h * D_ + d0]) = pk;
        }
    }
}

extern "C" void kernel_launch(void* const* d_in, const int* in_sizes, int n_in,
                              void* d_out, int out_size, void* d_ws, size_t ws_size,
                              hipStream_t stream) {
    const float* y = (const float*)d_in[0];
    const float* W_attn = (const float*)d_in[1];
    const float* b_attn = (const float*)d_in[2];
    const float* W_proj = (const float*)d_in[3];
    const float* b_proj = (const float*)d_in[4];

    char* ws = (char*)d_ws;
    u16* y_bf = (u16*)(ws);                                // 16 MB
    u16* WaT  = (u16*)(ws + 16777216);                     // 6 MB  [3072][1024]
    u16* WpT  = (u16*)(ws + 16777216 + 6291456);           // 2 MB  [1024][1024]
    u16* q_ws = (u16*)(ws + 25165824);                     // 16 MB [B,H,T,D] (prescaled)
    u16* k_ws = (u16*)(ws + 25165824 + 16777216);          // 16 MB [B,H,T,D]
    u16* v_ws = (u16*)(ws + 25165824 + 33554432);          // 16 MB [B,H,D,T]
    u16* attn = (u16*)(ws + 25165824 + 50331648);          // 16 MB [B,T,C]

    k_cast_bf16<<<8192, 256, 0, stream>>>(y, y_bf, B_ * T_ * C_);
    k_transpose_bf16<<<dim3(96, 32), dim3(32, 8), 0, stream>>>(W_attn, WaT, 1024, 3072);
    k_transpose_bf16<<<dim3(32, 32), dim3(32, 8), 0, stream>>>(W_proj, WpT, 1024, 1024);
    k_gemm<1><<<dim3(64, 24), 256, 0, stream>>>(y_bf, WaT, b_attn, 1024, 3072,
                                                nullptr, q_ws, k_ws, v_ws);
    k_attn<<<1024, 256, 0, stream>>>(q_ws, k_ws, v_ws, attn);
    k_gemm<0><<<dim3(64, 8), 256, 0, stream>>>(attn, WpT, b_proj, 1024, 1024,
                                               (float*)d_out, nullptr, nullptr, nullptr);
}

// Round 8
// 188.773 us; speedup vs baseline: 1.2138x; 1.0601x over previous
//
#include <hip/hip_runtime.h>
#include <hip/hip_bf16.h>
#include <stdint.h>

#define B_ 4
#define T_ 2048
#define C_ 1024
#define H_ 16
#define D_ 64

typedef short bf16x8 __attribute__((ext_vector_type(8)));
typedef float f32x4 __attribute__((ext_vector_type(4)));
typedef unsigned short u16;

// log2(e)/sqrt(D): folded into Q at the qkv epilogue -> scores in exp2 domain.
#define QSCALE 0.18033688011112042f

__device__ __forceinline__ u16 f2bf(float f) {
    __hip_bfloat16 h = __float2bfloat16(f);
    return *reinterpret_cast<u16*>(&h);
}

__device__ __forceinline__ float fexp2(float x) {
    float r;
    asm("v_exp_f32 %0, %1" : "=v"(r) : "v"(x));
    return r;
}

__device__ __forceinline__ void gload16(const void* g, void* l) {
    __builtin_amdgcn_global_load_lds(
        (const __attribute__((address_space(1))) unsigned int*)g,
        (__attribute__((address_space(3))) unsigned int*)l, 16, 0, 0);
}

// ---------------- prep: cast y -> bf16, transpose W_attn, W_proj ----------------
// One kernel, three blockIdx segments (saves 2 launches of graph-gap).
__global__ void k_prep(const float* __restrict__ y, u16* __restrict__ y_bf,
                       const float* __restrict__ Wa, u16* __restrict__ WaT,
                       const float* __restrict__ Wp, u16* __restrict__ WpT) {
    const int bid = blockIdx.x, tid = threadIdx.x;
    if (bid < 8192) {
        int i = (bid * 256 + tid) * 4;
        float4 f = *reinterpret_cast<const float4*>(y + i);
        ushort4 o;
        o.x = f2bf(f.x); o.y = f2bf(f.y); o.z = f2bf(f.z); o.w = f2bf(f.w);
        *reinterpret_cast<ushort4*>(y_bf + i) = o;
        return;
    }
    __shared__ float tile[32][33];
    const float* src; u16* dst; int R, Cc, bx, by;
    if (bid < 8192 + 3072) {
        int idx = bid - 8192;
        src = Wa; dst = WaT; R = 1024; Cc = 3072;
        bx = idx % 96; by = idx / 96;
    } else {
        int idx = bid - 11264;
        src = Wp; dst = WpT; R = 1024; Cc = 1024;
        bx = idx & 31; by = idx >> 5;
    }
    int c0 = bx * 32, r0 = by * 32;
    int tx = tid & 31, ty = tid >> 5;
#pragma unroll
    for (int i = 0; i < 4; i++)
        tile[ty + i * 8][tx] = src[(size_t)(r0 + ty + i * 8) * Cc + c0 + tx];
    __syncthreads();
#pragma unroll
    for (int i = 0; i < 4; i++)
        dst[(size_t)(c0 + ty + i * 8) * R + r0 + tx] = f2bf(tile[tx][ty + i * 8]);
}

// ---------------- GEMM (m97-style, known-good) ----------------
// C[M,N] = A[M,K] * Bt[N,K]^T + bias. 128x128 tile, BK=64, 4 waves of 64x64.
template <int EPI>
__launch_bounds__(256, 2)
__global__ void k_gemm(const u16* __restrict__ A, const u16* __restrict__ Bt,
                       const float* __restrict__ bias, int K, int N,
                       float* __restrict__ outf,
                       u16* __restrict__ qw, u16* __restrict__ kw, u16* __restrict__ vw) {
    __shared__ u16 As[128 * 64];
    __shared__ u16 Bs[128 * 64];
    const int tid = threadIdx.x;
    const int lane = tid & 63, w = tid >> 6;
    const int m0 = blockIdx.x * 128, n0 = blockIdx.y * 128;
    const int wm = (w >> 1) * 64, wn = (w & 1) * 64;
    const int lr = lane & 15, lg = lane >> 4;

    f32x4 acc[4][4];
#pragma unroll
    for (int i = 0; i < 4; i++)
#pragma unroll
        for (int j = 0; j < 4; j++) acc[i][j] = (f32x4){0.f, 0.f, 0.f, 0.f};

    const int nk = K >> 6;
    for (int kt = 0; kt < nk; ++kt) {
        const int k0 = kt * 64;
#pragma unroll
        for (int i = 0; i < 4; i++) {
            int c = i * 256 + tid;
            int row = c >> 3, k8 = (c & 7) << 3;
            gload16(A + (size_t)(m0 + row) * K + k0 + k8, (char*)As + i * 4096 + w * 1024);
            gload16(Bt + (size_t)(n0 + row) * K + k0 + k8, (char*)Bs + i * 4096 + w * 1024);
        }
        __syncthreads();
#pragma unroll
        for (int kk = 0; kk < 2; ++kk) {
            bf16x8 af[4], bfr[4];
#pragma unroll
            for (int mf = 0; mf < 4; ++mf)
                af[mf] = *reinterpret_cast<const bf16x8*>(&As[(wm + mf * 16 + lr) * 64 + kk * 32 + lg * 8]);
#pragma unroll
            for (int nf = 0; nf < 4; ++nf)
                bfr[nf] = *reinterpret_cast<const bf16x8*>(&Bs[(wn + nf * 16 + lr) * 64 + kk * 32 + lg * 8]);
#pragma unroll
            for (int mf = 0; mf < 4; ++mf)
#pragma unroll
                for (int nf = 0; nf < 4; ++nf)
                    acc[mf][nf] = __builtin_amdgcn_mfma_f32_16x16x32_bf16(af[mf], bfr[nf], acc[mf][nf], 0, 0, 0);
        }
        __syncthreads();
    }

    if (EPI == 0) {
#pragma unroll
        for (int mf = 0; mf < 4; ++mf)
#pragma unroll
            for (int nf = 0; nf < 4; ++nf) {
                int ng = n0 + wn + nf * 16 + lr;
                float bs = bias[ng];
#pragma unroll
                for (int r = 0; r < 4; ++r) {
                    int mg = m0 + wm + mf * 16 + lg * 4 + r;
                    outf[(size_t)mg * N + ng] = acc[mf][nf][r] + bs;
                }
            }
    } else {
        const int sec = n0 >> 10;  // 0:q 1:k 2:v — uniform per block
        const float sc = (sec == 0) ? QSCALE : 1.0f;  // Q prescaled into exp2 domain
#pragma unroll
        for (int mf = 0; mf < 4; ++mf)
#pragma unroll
            for (int nf = 0; nf < 4; ++nf) {
                int ng = n0 + wn + nf * 16 + lr;
                float bs = bias[ng];
                int hd = ng & 1023;
                int h = hd >> 6, d = hd & 63;
                int mgb = m0 + wm + mf * 16 + lg * 4;
                int b = mgb >> 11, t0v = mgb & 2047;
                if (sec == 2) {
                    ushort4 pk;
                    pk.x = f2bf(acc[mf][nf][0] + bs);
                    pk.y = f2bf(acc[mf][nf][1] + bs);
                    pk.z = f2bf(acc[mf][nf][2] + bs);
                    pk.w = f2bf(acc[mf][nf][3] + bs);
                    *reinterpret_cast<ushort4*>(&vw[((size_t)(b * H_ + h) * D_ + d) * T_ + t0v]) = pk;
                } else {
                    u16* dst = (sec == 0) ? qw : kw;
#pragma unroll
                    for (int r = 0; r < 4; ++r)
                        dst[((size_t)(b * H_ + h) * T_ + t0v + r) * D_ + d] = f2bf((acc[mf][nf][r] + bs) * sc);
                }
            }
    }
}

// ---------------- flash attention: 2 waves x 64 q-rows, all-x32 MFMA ----------------
// 128-thread blocks (2 waves), each wave owns 64 q-rows (jq=4): halves LDS
// read traffic per FLOP vs 4x32 (each wave reads the full K/V tile regardless
// of q-rows owned — round-6 lesson). Grid stays 1024 = 4 blocks/CU; 8 waves/CU
// at ~190 VGPR (2/SIMD cap). Permuted-K-row QK -> P lands in x32 B-operand
// layout, PV at full x32 rate, zero cross-lane movement, zero bank conflicts.
// Softmax: no-max exp2 (Q prescaled; |s|<~12 bounded => exact via shift-inv).
__launch_bounds__(128, 2)
__global__ void k_attn(const u16* __restrict__ qw, const u16* __restrict__ kw,
                       const u16* __restrict__ vw, u16* __restrict__ attn) {
    __shared__ u16 Ks[2][64][64];   // [buf][key][d]   rows 128B, sK-swizzled
    __shared__ u16 Vs[2][64][64];   // [buf][d][key]   rows 128B, (row&7)-swizzled
    const int tid = threadIdx.x, lane = tid & 63, w = tid >> 6;
    const int lr = lane & 15, lg = lane >> 4;
    const int bid = blockIdx.x;
    const int logical = (bid & 7) * 128 + (bid >> 3);  // bijective: 1024 = 8*128
    const int bh = logical >> 4, qb = logical & 15;
    const int b = bh >> 4, h = bh & 15;
    const int q0 = qb * 128 + w * 64;
    const u16* qbase = qw + (size_t)bh * T_ * D_;
    const u16* kbase = kw + (size_t)bh * T_ * D_;
    const u16* vbase = vw + (size_t)bh * D_ * T_;

    // Q as B-operand fragments: col = q-row (lr), k = d contiguous
    bf16x8 qf[4][2];
#pragma unroll
    for (int jq = 0; jq < 4; jq++)
#pragma unroll
        for (int kd = 0; kd < 2; kd++)
            qf[jq][kd] = *reinterpret_cast<const bf16x8*>(
                &qbase[(size_t)(q0 + jq * 16 + lr) * D_ + kd * 32 + lg * 8]);

    // stage one 64x64 tile (8KB): 128 threads x 4 chunks; dest linear,
    // source pre-inverse-swizzled (both-sides involution).
    auto stageK = [&](int kt, int buf) {
#pragma unroll
        for (int i = 0; i < 4; i++) {
            int idx = i * 128 + tid;
            int row = idx >> 3, ch = idx & 7;
            int gch = ch ^ ((row & 3) | (((row >> 3) & 1) << 2));
            gload16(kbase + ((size_t)(kt * 64 + row) * 64 + gch * 8),
                    (char*)&Ks[buf][0][0] + i * 2048 + w * 1024);
        }
    };
    auto stageV = [&](int kt, int buf) {
#pragma unroll
        for (int i = 0; i < 4; i++) {
            int idx = i * 128 + tid;
            int row = idx >> 3, ch = idx & 7;
            int gch = ch ^ (row & 7);
            gload16(vbase + ((size_t)row * T_ + kt * 64 + gch * 8),
                    (char*)&Vs[buf][0][0] + i * 2048 + w * 1024);
        }
    };

    f32x4 o[4][4];   // [md][jq]
#pragma unroll
    for (int md = 0; md < 4; md++)
#pragma unroll
        for (int jq = 0; jq < 4; jq++) o[md][jq] = (f32x4){0.f, 0.f, 0.f, 0.f};
    float l_run[4] = {0.f, 0.f, 0.f, 0.f};

    // permuted A-row base for QK (per-lane constants)
    const int karow_base = ((lr >> 2) << 3) + (lr & 3);
    const int skl = ((lr & 3) | (((lr >> 2) & 1) << 2)) << 4;  // byte-XOR for ka reads

    const int NT = T_ / 64;
    stageK(0, 0);
    stageV(0, 0);

    for (int kt = 0; kt < NT; ++kt) {
        const int cur = kt & 1;
        if (kt + 1 < NT) {
            stageK(kt + 1, cur ^ 1);
            stageV(kt + 1, cur ^ 1);
            asm volatile("s_waitcnt vmcnt(8)" ::: "memory");  // cur done, next in flight
        } else {
            asm volatile("s_waitcnt vmcnt(0)" ::: "memory");
        }
        __builtin_amdgcn_s_barrier();

        bf16x8 pfrag[4][2];  // [jq][g] — x32 B-operand frags, keys g*32 + lg*8 + e
#pragma unroll
        for (int g = 0; g < 2; g++) {
            f32x4 st[2][4];  // [tile][jq]
#pragma unroll
            for (int t = 0; t < 2; t++)
#pragma unroll
                for (int jq = 0; jq < 4; jq++) st[t][jq] = (f32x4){0.f, 0.f, 0.f, 0.f};
            __builtin_amdgcn_s_setprio(1);
#pragma unroll
            for (int t = 0; t < 2; t++) {
                int row = g * 32 + karow_base + t * 4;
#pragma unroll
                for (int kd = 0; kd < 2; kd++) {
                    bf16x8 ka = *reinterpret_cast<const bf16x8*>(
                        (const char*)&Ks[cur][0][0] + row * 128 + ((kd * 64 + lg * 16) ^ skl));
#pragma unroll
                    for (int jq = 0; jq < 4; jq++)
                        st[t][jq] = __builtin_amdgcn_mfma_f32_16x16x32_bf16(ka, qf[jq][kd], st[t][jq], 0, 0, 0);
                }
            }
            __builtin_amdgcn_s_setprio(0);
            // p = exp2(s) raw (no max); pack straight into the x32 fragment
#pragma unroll
            for (int jq = 0; jq < 4; jq++) {
                float p0 = fexp2(st[0][jq][0]), p1 = fexp2(st[0][jq][1]);
                float p2 = fexp2(st[0][jq][2]), p3 = fexp2(st[0][jq][3]);
                float p4 = fexp2(st[1][jq][0]), p5 = fexp2(st[1][jq][1]);
                float p6 = fexp2(st[1][jq][2]), p7 = fexp2(st[1][jq][3]);
                l_run[jq] += ((p0 + p1) + (p2 + p3)) + ((p4 + p5) + (p6 + p7));
                pfrag[jq][g] = (bf16x8){(short)f2bf(p0), (short)f2bf(p1),
                                        (short)f2bf(p2), (short)f2bf(p3),
                                        (short)f2bf(p4), (short)f2bf(p5),
                                        (short)f2bf(p6), (short)f2bf(p7)};
            }
        }

        // PV at full x32 rate: o += V^T[g] * P^T[g]
#pragma unroll
        for (int g = 0; g < 2; g++) {
            bf16x8 va[4];
#pragma unroll
            for (int md = 0; md < 4; md++) {
                int row = md * 16 + lr;
                va[md] = *reinterpret_cast<const bf16x8*>(
                    (const char*)&Vs[cur][0][0] + row * 128 + ((g * 64 + lg * 16) ^ ((row & 7) << 4)));
            }
            __builtin_amdgcn_s_setprio(1);
#pragma unroll
            for (int md = 0; md < 4; md++)
#pragma unroll
                for (int jq = 0; jq < 4; jq++)
                    o[md][jq] = __builtin_amdgcn_mfma_f32_16x16x32_bf16(va[md], pfrag[jq][g], o[md][jq], 0, 0, 0);
            __builtin_amdgcn_s_setprio(0);
        }

        __builtin_amdgcn_s_barrier();  // all waves done reading buf before overwrite
    }

    // epilogue: reduce l across the 4 lanes holding this q-row, then normalize.
#pragma unroll
    for (int jq = 0; jq < 4; jq++) {
        float l = l_run[jq];
        l += __shfl_xor(l, 16);
        l += __shfl_xor(l, 32);
        float rinv = 1.f / l;
        int q = q0 + jq * 16 + lr;
#pragma unroll
        for (int md = 0; md < 4; md++) {
            int d0 = md * 16 + lg * 4;
            ushort4 pk;
            pk.x = f2bf(o[md][jq][0] * rinv);
            pk.y = f2bf(o[md][jq][1] * rinv);
            pk.z = f2bf(o[md][jq][2] * rinv);
            pk.w = f2bf(o[md][jq][3] * rinv);
            *reinterpret_cast<ushort4*>(&attn[((size_t)(b * T_ + q)) * C_ + h * D_ + d0]) = pk;
        }
    }
}

extern "C" void kernel_launch(void* const* d_in, const int* in_sizes, int n_in,
                              void* d_out, int out_size, void* d_ws, size_t ws_size,
                              hipStream_t stream) {
    const float* y = (const float*)d_in[0];
    const float* W_attn = (const float*)d_in[1];
    const float* b_attn = (const float*)d_in[2];
    const float* W_proj = (const float*)d_in[3];
    const float* b_proj = (const float*)d_in[4];

    char* ws = (char*)d_ws;
    u16* y_bf = (u16*)(ws);                                // 16 MB
    u16* WaT  = (u16*)(ws + 16777216);                     // 6 MB  [3072][1024]
    u16* WpT  = (u16*)(ws + 16777216 + 6291456);           // 2 MB  [1024][1024]
    u16* q_ws = (u16*)(ws + 25165824);                     // 16 MB [B,H,T,D] (prescaled)
    u16* k_ws = (u16*)(ws + 25165824 + 16777216);          // 16 MB [B,H,T,D]
    u16* v_ws = (u16*)(ws + 25165824 + 33554432);          // 16 MB [B,H,D,T]
    u16* attn = (u16*)(ws + 25165824 + 50331648);          // 16 MB [B,T,C]

    k_prep<<<12288, 256, 0, stream>>>(y, y_bf, W_attn, WaT, W_proj, WpT);
    k_gemm<1><<<dim3(64, 24), 256, 0, stream>>>(y_bf, WaT, b_attn, 1024, 3072,
                                                nullptr, q_ws, k_ws, v_ws);
    k_attn<<<1024, 128, 0, stream>>>(q_ws, k_ws, v_ws, attn);
    k_gemm<0><<<dim3(64, 8), 256, 0, stream>>>(attn, WpT, b_proj, 1024, 1024,
                                               (float*)d_out, nullptr, nullptr, nullptr);
}